// Round 7
// baseline (269.491 us; speedup 1.0000x reference)
//
#include <hip/hip_runtime.h>
#include <stdint.h>

#define SEQ   2048
#define NDIM  1024
#define NH    16
#define HD    64
#define KDIM  1024

typedef short  short8  __attribute__((ext_vector_type(8)));
typedef float  floatx4 __attribute__((ext_vector_type(4)));
typedef unsigned short ushort4v __attribute__((ext_vector_type(4)));
typedef _Float16 half8 __attribute__((ext_vector_type(8)));
typedef __fp16  fp16x2 __attribute__((ext_vector_type(2)));
typedef unsigned int uint2v __attribute__((ext_vector_type(2)));
typedef unsigned int uint4v __attribute__((ext_vector_type(4)));

typedef __attribute__((address_space(1))) void GV;   // global AS
typedef __attribute__((address_space(3))) void LV;   // LDS AS

#define QSCALE 0.04508422003f   // log2(e)/32  (folded into Q at GEMM1 epilogue)

__device__ __forceinline__ unsigned short f2bf(float f) {
    unsigned int u = __float_as_uint(f);
    u += 0x7fffu + ((u >> 16) & 1u);     // round-to-nearest-even
    return (unsigned short)(u >> 16);
}

__device__ __forceinline__ float ex2(float x) {
#if __has_builtin(__builtin_amdgcn_exp2f)
    return __builtin_amdgcn_exp2f(x);    // bare v_exp_f32, no libm fixup
#else
    return exp2f(x);
#endif
}

// ---------------------------------------------------------------- merged cast kernel
__global__ __launch_bounds__(256) void cast_all(const float* __restrict__ x,
                                                const float* __restrict__ wqkv,
                                                const float* __restrict__ wout,
                                                unsigned short* __restrict__ out) {
    const int bid = blockIdx.x;
    const int i = (bid * 256 + threadIdx.x) * 4;
    const float* src;
    if (bid < 8192)        src = x    + i;
    else if (bid < 11264)  src = wqkv + (i - 8388608);
    else                   src = wout + (i - 11534336);
    float4 v = *(const float4*)src;
    ushort4v o;
    o.x = f2bf(v.x); o.y = f2bf(v.y); o.z = f2bf(v.z); o.w = f2bf(v.w);
    *(ushort4v*)(out + i) = o;
}

// ---------------------------------------------------------------- GEMM (C = A * B^T), bf16 in, fp32 acc
// async double-buffered staging — ONE barrier per K-tile; (256,4) = 4
// independent barrier-groups per CU (validated R5: gemm0 88.9 -> <86.5).
// R7: K/V scatter epilogue reverted to the R1 16x16-fragment formats,
// coupled with the attn v7 revert (see attn comment for the v7-v10 series
// post-mortem: per-wave LDS-reuse tricks that cost VGPR>64 halve waves/SIMD
// and serialize the pipes; v7 @ 32 waves/CU is the measured optimum).
// MODE 0: qkv scatter epilogue (Q pre-scaled; K/V in 16x16 attn fragment order)
// MODE 1: fp32 out + bias epilogue
template<int MODE>
__global__ __launch_bounds__(256, 4)
void gemm_bt(const unsigned short* __restrict__ A,
             const unsigned short* __restrict__ B,
             unsigned short* __restrict__ Cq,
             unsigned short* __restrict__ Ck,
             unsigned short* __restrict__ Cv,
             const float* __restrict__ bias,
             float* __restrict__ Cout)
{
    __shared__ unsigned short As[2][4096];
    __shared__ unsigned short Bs[2][4096];
    const int tid  = threadIdx.x;
    const int lane = tid & 63;
    const int w    = tid >> 6;
    const int quad = lane >> 4;
    const int l15  = lane & 15;
    const int wm   = w >> 1, wn = w & 1;
    const int bm   = blockIdx.x, bn = blockIdx.y;

    const unsigned short* Arow = A + (size_t)bm * 128 * KDIM;
    const unsigned short* Brow = B + (size_t)bn * 128 * KDIM;

    const unsigned short* ga[2]; const unsigned short* gb[2];
    unsigned short* la[2][2];    unsigned short* lb[2][2];
#pragma unroll
    for (int i = 0; i < 2; ++i) {
        int j = ((w * 2 + i) << 6) + lane;
        int r = j >> 2;
        int c = (j & 3) ^ ((r >> 1) & 3);
        ga[i] = Arow + r * KDIM + c * 8;
        gb[i] = Brow + r * KDIM + c * 8;
#pragma unroll
        for (int b = 0; b < 2; ++b) {
            la[b][i] = &As[b][(w * 2 + i) << 9];
            lb[b][i] = &Bs[b][(w * 2 + i) << 9];
        }
    }

    int achunk[4], bchunk[4];
#pragma unroll
    for (int t = 0; t < 4; ++t) {
        int ra = wm * 64 + t * 16 + l15;
        achunk[t] = (ra << 2) + (quad ^ ((ra >> 1) & 3));
        int rb = wn * 64 + t * 16 + l15;
        bchunk[t] = (rb << 2) + (quad ^ ((rb >> 1) & 3));
    }

    floatx4 acc[4][4];
#pragma unroll
    for (int mt = 0; mt < 4; ++mt)
#pragma unroll
        for (int nt = 0; nt < 4; ++nt)
            acc[mt][nt] = (floatx4){0.f, 0.f, 0.f, 0.f};

    // prologue: DMA K-tile 0 into buffer 0
#pragma unroll
    for (int i = 0; i < 2; ++i) {
        __builtin_amdgcn_global_load_lds((GV*)(void*)ga[i], (LV*)(void*)la[0][i], 16, 0, 0);
        __builtin_amdgcn_global_load_lds((GV*)(void*)gb[i], (LV*)(void*)lb[0][i], 16, 0, 0);
    }

    for (int kt = 0; kt < KDIM / 32; ++kt) {
        const int buf = kt & 1;
        __syncthreads();   // drains DMA for buf (issued a full compute phase ago)
        if (kt < KDIM / 32 - 1) {
#pragma unroll
            for (int i = 0; i < 2; ++i) {
                __builtin_amdgcn_global_load_lds((GV*)(void*)(ga[i] + (kt + 1) * 32), (LV*)(void*)la[buf ^ 1][i], 16, 0, 0);
                __builtin_amdgcn_global_load_lds((GV*)(void*)(gb[i] + (kt + 1) * 32), (LV*)(void*)lb[buf ^ 1][i], 16, 0, 0);
            }
        }
        short8 af[4], bf[4];
#pragma unroll
        for (int t = 0; t < 4; ++t) {
            af[t] = *(const short8*)(&As[buf][0] + (achunk[t] << 3));
            bf[t] = *(const short8*)(&Bs[buf][0] + (bchunk[t] << 3));
        }
#pragma unroll
        for (int mt = 0; mt < 4; ++mt)
#pragma unroll
            for (int nt = 0; nt < 4; ++nt)
                acc[mt][nt] = __builtin_amdgcn_mfma_f32_16x16x32_bf16(af[mt], bf[nt], acc[mt][nt], 0, 0, 0);
    }

    if (MODE == 0) {
        const int which = bn >> 3;  // 0=q 1=k 2=v
        unsigned short* dst = which == 0 ? Cq : (which == 1 ? Ck : Cv);
        if (which == 2) {
            // V: one 8B store per (nt,mt) — r=0..3 are consecutive j  (R1 format)
#pragma unroll
            for (int nt = 0; nt < 4; ++nt) {
                int e0   = ((bn & 7) << 7) + wn * 64 + nt * 16;
                int head = e0 >> 6;
                int hdi  = (e0 & 63) + l15;
#pragma unroll
                for (int mt = 0; mt < 4; ++mt) {
                    int n0 = bm * 128 + wm * 64 + mt * 16 + quad * 4;
                    int b  = n0 >> 11;
                    int n  = n0 & 2047;
                    int bh = (b << 4) + head;
                    int u  = (n & 127) >> 5;
                    size_t base = (size_t)bh * 131072
                                + (size_t)(n >> 7) * 8192
                                + (size_t)(u * 4 + ((hdi >> 4) & 3)) * 512
                                + (quad * 16 + (hdi & 15)) * 8
                                + ((mt & 1) << 2);
                    fp16x2 p01 = __builtin_amdgcn_cvt_pkrtz(acc[mt][nt][0], acc[mt][nt][1]);
                    fp16x2 p23 = __builtin_amdgcn_cvt_pkrtz(acc[mt][nt][2], acc[mt][nt][3]);
                    uint2v st;
                    st.x = __builtin_bit_cast(unsigned int, p01);
                    st.y = __builtin_bit_cast(unsigned int, p23);
                    *(uint2v*)(dst + base) = st;
                }
            }
        } else {
#pragma unroll
            for (int nt = 0; nt < 4; ++nt) {
                int e0   = ((bn & 7) << 7) + wn * 64 + nt * 16;
                int head = e0 >> 6;
                int hdi  = (e0 & 63) + l15;
#pragma unroll
                for (int mt = 0; mt < 4; ++mt) {
#pragma unroll
                    for (int r = 0; r < 4; ++r) {
                        int m = bm * 128 + wm * 64 + mt * 16 + quad * 4 + r;
                        int b = m >> 11, n = m & 2047;
                        int bh = (b << 4) + head;
                        float val = acc[mt][nt][r];
                        if (which == 0) {
                            dst[((size_t)bh * SEQ + n) * HD + hdi] = f2bf(val * QSCALE);
                        } else {
                            size_t idx = (size_t)bh * 131072
                                       + (size_t)(n >> 7) * 8192
                                       + (size_t)((((n >> 4) & 7) * 2) + (hdi >> 5)) * 512
                                       + ((((hdi >> 3) & 3) * 16) + (n & 15)) * 8
                                       + (hdi & 7);
                            dst[idx] = f2bf(val);
                        }
                    }
                }
            }
        }
    } else {
#pragma unroll
        for (int nt = 0; nt < 4; ++nt) {
            int e = bn * 128 + wn * 64 + nt * 16 + l15;
            float bv = bias[e];
#pragma unroll
            for (int mt = 0; mt < 4; ++mt) {
#pragma unroll
                for (int r = 0; r < 4; ++r) {
                    int m = bm * 128 + wm * 64 + mt * 16 + quad * 4 + r;
                    Cout[(size_t)m * NDIM + e] = acc[mt][nt][r] + bv;
                }
            }
        }
    }
}

// ---------------------------------------------------------------- flash attention, v7 (RESTORED — measured optimum)
// v7-v10 series post-mortem: v7(16x16, 1x LDS, 32 waves/CU, VGPR 32)=77.2us;
// v8(32x32, 0.5x LDS, 16 waves)=85.8; v9(0.25x LDS, 8 waves)=86.6;
// v10(=v9 @128thr, VGPR 96)=94.4. Law: LDS-reuse tricks that push VGPR past
// the 64-reg occupancy cliff halve waves/SIMD and serialize MFMA/VALU/LDS
// phases — TLP beats per-wave efficiency here. v7 runs at its ds_read_b128
// issue ceiling (~91 B/cyc/CU) with pipes overlapped by 32 waves/CU.
// 512 threads = 8 waves x 16 q-rows; 64-key async double-buffered subtiles.
__global__ __launch_bounds__(512, 8)
void attn_fused(const unsigned short* __restrict__ qb,
                const unsigned short* __restrict__ kfrag,   // bf16 fragment-order
                const unsigned short* __restrict__ vfrag,   // fp16 fragment-order
                unsigned short* __restrict__ ob)            // bf16 [b][n][1024]
{
    __shared__ unsigned short Ks[2][4096];   // 64-key K subtile x2 (16 KB)
    __shared__ unsigned short Vs[2][4096];   // 64-key V subtile x2 (16 KB)

    const int tid  = threadIdx.x;
    const int lane = tid & 63;
    const int w    = tid >> 6;              // 0..7
    const int quad = lane >> 4;
    const int l15  = lane & 15;

    const int bid  = blockIdx.x;
    const int xcd  = bid & 7;
    const int slot = bid >> 3;
    const int bh   = xcd * 8 + (slot >> 4);   // 8 bh per XCD
    const int q0   = (slot & 15) * 128;

    const unsigned short* Qb = qb    + (size_t)bh * SEQ * HD;
    const unsigned short* Kb = kfrag + (size_t)bh * 131072;
    const unsigned short* Vb = vfrag + (size_t)bh * 131072;

    // Q fragments (MFMA B operand): rows q0 + w*16 + l15 (pre-scaled)
    short8 qf[2];
#pragma unroll
    for (int ks = 0; ks < 2; ++ks)
        qf[ks] = *(const short8*)(Qb + (size_t)(q0 + w * 16 + l15) * HD + ks * 32 + quad * 8);

    floatx4 oacc[4];   // O[q=quad*4+r][hd=nt*16+l15]
#pragma unroll
    for (int nt = 0; nt < 4; ++nt) oacc[nt] = (floatx4){0.f, 0.f, 0.f, 0.f};
    floatx4 lacc = (floatx4){0.f, 0.f, 0.f, 0.f};   // l[q=quad*4+r]

    half8 vones;
#pragma unroll
    for (int i = 0; i < 8; ++i) vones[i] = (_Float16)1.0f;

    // staging: 8 waves x 64 lanes x 16B = one full 64-key subtile (K and V)
    const unsigned short* gk = Kb + (size_t)((w << 6) + lane) * 8;
    const unsigned short* gv = Vb + (size_t)((w << 6) + lane) * 8;
    unsigned short* lk[2] = { &Ks[0][w << 9], &Ks[1][w << 9] };
    unsigned short* lv[2] = { &Vs[0][w << 9], &Vs[1][w << 9] };

    // prologue: DMA subtile 0 into buffer 0
    __builtin_amdgcn_global_load_lds((GV*)(void*)gk, (LV*)(void*)lk[0], 16, 0, 0);
    __builtin_amdgcn_global_load_lds((GV*)(void*)gv, (LV*)(void*)lv[0], 16, 0, 0);

    for (int t = 0; t < 32; ++t) {
        const int buf = t & 1;
        __syncthreads();
        if (t < 31) {
            __builtin_amdgcn_global_load_lds((GV*)(void*)(gk + (t + 1) * 4096), (LV*)(void*)lk[buf ^ 1], 16, 0, 0);
            __builtin_amdgcn_global_load_lds((GV*)(void*)(gv + (t + 1) * 4096), (LV*)(void*)lv[buf ^ 1], 16, 0, 0);
        }
        const unsigned short* KsB = Ks[buf];
        const unsigned short* VsB = Vs[buf];

        // ---- S^T = K * Q^T over 64 keys
        floatx4 sacc[4];
#pragma unroll
        for (int nt = 0; nt < 4; ++nt) sacc[nt] = (floatx4){0.f, 0.f, 0.f, 0.f};

        __builtin_amdgcn_s_setprio(1);
#pragma unroll
        for (int ks = 0; ks < 2; ++ks) {
#pragma unroll
            for (int nt = 0; nt < 4; ++nt) {
                short8 kf = *(const short8*)(KsB + (nt * 2 + ks) * 512 + lane * 8);
                sacc[nt] = __builtin_amdgcn_mfma_f32_16x16x32_bf16(kf, qf[ks], sacc[nt], 0, 0, 0);
            }
        }
        __builtin_amdgcn_s_setprio(0);

        // ---- softmax + PV over 32-key groups (native 16x16x32 f16)
#pragma unroll
        for (int u = 0; u < 2; ++u) {
            floatx4 s0 = sacc[2 * u];
            floatx4 s1 = sacc[2 * u + 1];
            fp16x2 c0 = __builtin_amdgcn_cvt_pkrtz(ex2(s0[0]), ex2(s0[1]));
            fp16x2 c1 = __builtin_amdgcn_cvt_pkrtz(ex2(s0[2]), ex2(s0[3]));
            fp16x2 c2 = __builtin_amdgcn_cvt_pkrtz(ex2(s1[0]), ex2(s1[1]));
            fp16x2 c3 = __builtin_amdgcn_cvt_pkrtz(ex2(s1[2]), ex2(s1[3]));
            uint4v uu;
            uu.x = __builtin_bit_cast(unsigned int, c0);
            uu.y = __builtin_bit_cast(unsigned int, c1);
            uu.z = __builtin_bit_cast(unsigned int, c2);
            uu.w = __builtin_bit_cast(unsigned int, c3);
            half8 pf = __builtin_bit_cast(half8, uu);
            lacc = __builtin_amdgcn_mfma_f32_16x16x32_f16(pf, vones, lacc, 0, 0, 0);

            __builtin_amdgcn_s_setprio(1);
#pragma unroll
            for (int nt = 0; nt < 4; ++nt) {
                uint4v vv = *(const uint4v*)(VsB + (u * 4 + nt) * 512 + lane * 8);
                half8 vf = __builtin_bit_cast(half8, vv);
                oacc[nt] = __builtin_amdgcn_mfma_f32_16x16x32_f16(pf, vf, oacc[nt], 0, 0, 0);
            }
            __builtin_amdgcn_s_setprio(0);
        }
    }

    // ---- epilogue: O /= l, write bf16
    const int b = bh >> 4, h = bh & 15;
#pragma unroll
    for (int r = 0; r < 4; ++r) {
        float inv = 1.f / lacc[r];
        int n = q0 + w * 16 + quad * 4 + r;
        size_t rowoff = ((size_t)b * SEQ + n) * NDIM + h * HD;
#pragma unroll
        for (int nt = 0; nt < 4; ++nt)
            ob[rowoff + nt * 16 + l15] = f2bf(oacc[nt][r] * inv);
    }
}

// ---------------------------------------------------------------- launch
extern "C" void kernel_launch(void* const* d_in, const int* in_sizes, int n_in,
                              void* d_out, int out_size, void* d_ws, size_t ws_size,
                              hipStream_t stream)
{
    (void)in_sizes; (void)n_in; (void)out_size; (void)ws_size;
    const float* x    = (const float*)d_in[0];
    const float* wqkv = (const float*)d_in[1];
    const float* wout = (const float*)d_in[2];
    const float* bout = (const float*)d_in[3];
    float* out = (float*)d_out;

    unsigned short* xb    = (unsigned short*)d_ws;
    unsigned short* wqkvb = xb    + 8388608;
    unsigned short* woutb = wqkvb + 3145728;
    unsigned short* qbuf  = woutb + 1048576;
    unsigned short* kbuf  = qbuf  + 8388608;
    unsigned short* vbuf  = kbuf  + 8388608;
    unsigned short* obuf  = vbuf  + 8388608;

    cast_all<<<12288, 256, 0, stream>>>(x, wqkv, wout, xb);

    gemm_bt<0><<<dim3(64, 24), 256, 0, stream>>>(xb, wqkvb, qbuf, kbuf, vbuf, nullptr, nullptr);
    attn_fused<<<1024, 512, 0, stream>>>(qbuf, kbuf, vbuf, obuf);
    gemm_bt<1><<<dim3(64, 8), 256, 0, stream>>>(obuf, woutb, nullptr, nullptr, nullptr, bout, out);
}

// Round 8
// 266.643 us; speedup vs baseline: 1.0107x; 1.0107x over previous
//
#include <hip/hip_runtime.h>
#include <stdint.h>

#define SEQ   2048
#define NDIM  1024
#define NH    16
#define HD    64
#define KDIM  1024

typedef short  short8  __attribute__((ext_vector_type(8)));
typedef float  floatx4 __attribute__((ext_vector_type(4)));
typedef unsigned short ushort4v __attribute__((ext_vector_type(4)));
typedef _Float16 half8 __attribute__((ext_vector_type(8)));
typedef __fp16  fp16x2 __attribute__((ext_vector_type(2)));
typedef unsigned int uint2v __attribute__((ext_vector_type(2)));
typedef unsigned int uint4v __attribute__((ext_vector_type(4)));

typedef __attribute__((address_space(1))) void GV;   // global AS
typedef __attribute__((address_space(3))) void LV;   // LDS AS

#define QSCALE 0.04508422003f   // log2(e)/32  (folded into Q at GEMM1 epilogue)

__device__ __forceinline__ unsigned short f2bf(float f) {
    unsigned int u = __float_as_uint(f);
    u += 0x7fffu + ((u >> 16) & 1u);     // round-to-nearest-even
    return (unsigned short)(u >> 16);
}

__device__ __forceinline__ float ex2(float x) {
#if __has_builtin(__builtin_amdgcn_exp2f)
    return __builtin_amdgcn_exp2f(x);    // bare v_exp_f32, no libm fixup
#else
    return exp2f(x);
#endif
}

// ---------------------------------------------------------------- merged cast kernel
__global__ __launch_bounds__(256) void cast_all(const float* __restrict__ x,
                                                const float* __restrict__ wqkv,
                                                const float* __restrict__ wout,
                                                unsigned short* __restrict__ out) {
    const int bid = blockIdx.x;
    const int i = (bid * 256 + threadIdx.x) * 4;
    const float* src;
    if (bid < 8192)        src = x    + i;
    else if (bid < 11264)  src = wqkv + (i - 8388608);
    else                   src = wout + (i - 11534336);
    float4 v = *(const float4*)src;
    ushort4v o;
    o.x = f2bf(v.x); o.y = f2bf(v.y); o.z = f2bf(v.z); o.w = f2bf(v.w);
    *(ushort4v*)(out + i) = o;
}

// ---------------------------------------------------------------- GEMM (C = A * B^T), bf16 in, fp32 acc
// async double-buffered staging — ONE barrier per K-tile; (256,4) = 4
// independent barrier-groups per CU (validated: gemm0 88.9 -> 79.0 us).
// R8: Q epilogue vectorized. Q layout is free to choose (only the attn
// prologue reads it, 256 KB total), so Q now uses the r-contiguous
// fragment layout  addr = bh*131072 + (n>>4)*1024 + hd*16 + (n&15):
// the 4 acc values (n&15 = quad*4+r) pack into ONE 8B store, and lanes
// (quad,l15) tile a fully contiguous 2048B region per wave-store ->
// 16 store instrs @100% line utilization vs 64 scalar 2B stores @~50%.
// MODE 0: qkv scatter epilogue (Q pre-scaled frag-order; K/V 16x16 frag order)
// MODE 1: fp32 out + bias epilogue
template<int MODE>
__global__ __launch_bounds__(256, 4)
void gemm_bt(const unsigned short* __restrict__ A,
             const unsigned short* __restrict__ B,
             unsigned short* __restrict__ Cq,
             unsigned short* __restrict__ Ck,
             unsigned short* __restrict__ Cv,
             const float* __restrict__ bias,
             float* __restrict__ Cout)
{
    __shared__ unsigned short As[2][4096];
    __shared__ unsigned short Bs[2][4096];
    const int tid  = threadIdx.x;
    const int lane = tid & 63;
    const int w    = tid >> 6;
    const int quad = lane >> 4;
    const int l15  = lane & 15;
    const int wm   = w >> 1, wn = w & 1;
    const int bm   = blockIdx.x, bn = blockIdx.y;

    const unsigned short* Arow = A + (size_t)bm * 128 * KDIM;
    const unsigned short* Brow = B + (size_t)bn * 128 * KDIM;

    const unsigned short* ga[2]; const unsigned short* gb[2];
    unsigned short* la[2][2];    unsigned short* lb[2][2];
#pragma unroll
    for (int i = 0; i < 2; ++i) {
        int j = ((w * 2 + i) << 6) + lane;
        int r = j >> 2;
        int c = (j & 3) ^ ((r >> 1) & 3);
        ga[i] = Arow + r * KDIM + c * 8;
        gb[i] = Brow + r * KDIM + c * 8;
#pragma unroll
        for (int b = 0; b < 2; ++b) {
            la[b][i] = &As[b][(w * 2 + i) << 9];
            lb[b][i] = &Bs[b][(w * 2 + i) << 9];
        }
    }

    int achunk[4], bchunk[4];
#pragma unroll
    for (int t = 0; t < 4; ++t) {
        int ra = wm * 64 + t * 16 + l15;
        achunk[t] = (ra << 2) + (quad ^ ((ra >> 1) & 3));
        int rb = wn * 64 + t * 16 + l15;
        bchunk[t] = (rb << 2) + (quad ^ ((rb >> 1) & 3));
    }

    floatx4 acc[4][4];
#pragma unroll
    for (int mt = 0; mt < 4; ++mt)
#pragma unroll
        for (int nt = 0; nt < 4; ++nt)
            acc[mt][nt] = (floatx4){0.f, 0.f, 0.f, 0.f};

    // prologue: DMA K-tile 0 into buffer 0
#pragma unroll
    for (int i = 0; i < 2; ++i) {
        __builtin_amdgcn_global_load_lds((GV*)(void*)ga[i], (LV*)(void*)la[0][i], 16, 0, 0);
        __builtin_amdgcn_global_load_lds((GV*)(void*)gb[i], (LV*)(void*)lb[0][i], 16, 0, 0);
    }

    for (int kt = 0; kt < KDIM / 32; ++kt) {
        const int buf = kt & 1;
        __syncthreads();   // drains DMA for buf (issued a full compute phase ago)
        if (kt < KDIM / 32 - 1) {
#pragma unroll
            for (int i = 0; i < 2; ++i) {
                __builtin_amdgcn_global_load_lds((GV*)(void*)(ga[i] + (kt + 1) * 32), (LV*)(void*)la[buf ^ 1][i], 16, 0, 0);
                __builtin_amdgcn_global_load_lds((GV*)(void*)(gb[i] + (kt + 1) * 32), (LV*)(void*)lb[buf ^ 1][i], 16, 0, 0);
            }
        }
        short8 af[4], bf[4];
#pragma unroll
        for (int t = 0; t < 4; ++t) {
            af[t] = *(const short8*)(&As[buf][0] + (achunk[t] << 3));
            bf[t] = *(const short8*)(&Bs[buf][0] + (bchunk[t] << 3));
        }
#pragma unroll
        for (int mt = 0; mt < 4; ++mt)
#pragma unroll
            for (int nt = 0; nt < 4; ++nt)
                acc[mt][nt] = __builtin_amdgcn_mfma_f32_16x16x32_bf16(af[mt], bf[nt], acc[mt][nt], 0, 0, 0);
    }

    if (MODE == 0) {
        const int which = bn >> 3;  // 0=q 1=k 2=v
        unsigned short* dst = which == 0 ? Cq : (which == 1 ? Ck : Cv);
        if (which == 2) {
            // V: one 8B store per (nt,mt) — r=0..3 are consecutive j
#pragma unroll
            for (int nt = 0; nt < 4; ++nt) {
                int e0   = ((bn & 7) << 7) + wn * 64 + nt * 16;
                int head = e0 >> 6;
                int hdi  = (e0 & 63) + l15;
#pragma unroll
                for (int mt = 0; mt < 4; ++mt) {
                    int n0 = bm * 128 + wm * 64 + mt * 16 + quad * 4;
                    int b  = n0 >> 11;
                    int n  = n0 & 2047;
                    int bh = (b << 4) + head;
                    int u  = (n & 127) >> 5;
                    size_t base = (size_t)bh * 131072
                                + (size_t)(n >> 7) * 8192
                                + (size_t)(u * 4 + ((hdi >> 4) & 3)) * 512
                                + (quad * 16 + (hdi & 15)) * 8
                                + ((mt & 1) << 2);
                    fp16x2 p01 = __builtin_amdgcn_cvt_pkrtz(acc[mt][nt][0], acc[mt][nt][1]);
                    fp16x2 p23 = __builtin_amdgcn_cvt_pkrtz(acc[mt][nt][2], acc[mt][nt][3]);
                    uint2v st;
                    st.x = __builtin_bit_cast(unsigned int, p01);
                    st.y = __builtin_bit_cast(unsigned int, p23);
                    *(uint2v*)(dst + base) = st;
                }
            }
        } else if (which == 0) {
            // Q: r-contiguous fragment layout — one 8B packed store per (nt,mt)
#pragma unroll
            for (int nt = 0; nt < 4; ++nt) {
                int e0   = ((bn & 7) << 7) + wn * 64 + nt * 16;
                int head = e0 >> 6;
                int hd   = (e0 & 63) + l15;
#pragma unroll
                for (int mt = 0; mt < 4; ++mt) {
                    int n0 = bm * 128 + wm * 64 + mt * 16 + quad * 4;
                    int b  = n0 >> 11;
                    int n  = n0 & 2047;
                    int bh = (b << 4) + head;
                    size_t base = (size_t)bh * 131072
                                + (size_t)(n >> 4) * 1024
                                + (size_t)hd * 16
                                + (quad << 2);
                    unsigned short o0 = f2bf(acc[mt][nt][0] * QSCALE);
                    unsigned short o1 = f2bf(acc[mt][nt][1] * QSCALE);
                    unsigned short o2 = f2bf(acc[mt][nt][2] * QSCALE);
                    unsigned short o3 = f2bf(acc[mt][nt][3] * QSCALE);
                    uint2v st;
                    st.x = (unsigned int)o0 | ((unsigned int)o1 << 16);
                    st.y = (unsigned int)o2 | ((unsigned int)o3 << 16);
                    *(uint2v*)(dst + base) = st;
                }
            }
        } else {
            // K: 16x16 attn fragment order (layout fixed by attn hot loop)
#pragma unroll
            for (int nt = 0; nt < 4; ++nt) {
                int e0   = ((bn & 7) << 7) + wn * 64 + nt * 16;
                int head = e0 >> 6;
                int hdi  = (e0 & 63) + l15;
#pragma unroll
                for (int mt = 0; mt < 4; ++mt) {
#pragma unroll
                    for (int r = 0; r < 4; ++r) {
                        int m = bm * 128 + wm * 64 + mt * 16 + quad * 4 + r;
                        int b = m >> 11, n = m & 2047;
                        int bh = (b << 4) + head;
                        size_t idx = (size_t)bh * 131072
                                   + (size_t)(n >> 7) * 8192
                                   + (size_t)((((n >> 4) & 7) * 2) + (hdi >> 5)) * 512
                                   + ((((hdi >> 3) & 3) * 16) + (n & 15)) * 8
                                   + (hdi & 7);
                        dst[idx] = f2bf(acc[mt][nt][r]);
                    }
                }
            }
        }
    } else {
#pragma unroll
        for (int nt = 0; nt < 4; ++nt) {
            int e = bn * 128 + wn * 64 + nt * 16 + l15;
            float bv = bias[e];
#pragma unroll
            for (int mt = 0; mt < 4; ++mt) {
#pragma unroll
                for (int r = 0; r < 4; ++r) {
                    int m = bm * 128 + wm * 64 + mt * 16 + quad * 4 + r;
                    Cout[(size_t)m * NDIM + e] = acc[mt][nt][r] + bv;
                }
            }
        }
    }
}

// ---------------------------------------------------------------- flash attention, v7 + frag-order Q load
// v7 = measured optimum (32 waves/CU, LDS-issue-ceiling-bound with pipes
// overlapped; see R6 post-mortem series). R8 delta: Q is now stored in the
// r-contiguous fragment layout addr = bh*131072 + (n>>4)*1024 + hd*16 + (n&15)
// (chosen for gemm0's epilogue); the one-time Q prologue load becomes a
// 16-element gather per fragment (L2-hit, negligible: 256 KB total).
__global__ __launch_bounds__(512, 8)
void attn_fused(const unsigned short* __restrict__ qb,
                const unsigned short* __restrict__ kfrag,   // bf16 fragment-order
                const unsigned short* __restrict__ vfrag,   // fp16 fragment-order
                unsigned short* __restrict__ ob)            // bf16 [b][n][1024]
{
    __shared__ unsigned short Ks[2][4096];   // 64-key K subtile x2 (16 KB)
    __shared__ unsigned short Vs[2][4096];   // 64-key V subtile x2 (16 KB)

    const int tid  = threadIdx.x;
    const int lane = tid & 63;
    const int w    = tid >> 6;              // 0..7
    const int quad = lane >> 4;
    const int l15  = lane & 15;

    const int bid  = blockIdx.x;
    const int xcd  = bid & 7;
    const int slot = bid >> 3;
    const int bh   = xcd * 8 + (slot >> 4);   // 8 bh per XCD
    const int q0   = (slot & 15) * 128;

    const unsigned short* Qb = qb    + (size_t)bh * SEQ * HD;
    const unsigned short* Kb = kfrag + (size_t)bh * 131072;
    const unsigned short* Vb = vfrag + (size_t)bh * 131072;

    // Q fragments (MFMA B operand): q = q0 + w*16 + l15, k = ks*32 + quad*8 + e
    // frag-order layout: addr = (n>>4)*1024 + hd*16 + (n&15)
    short8 qf[2];
    {
        const unsigned short* qbase = Qb + (size_t)((q0 + w * 16) >> 4) * 1024 + l15;
#pragma unroll
        for (int ks = 0; ks < 2; ++ks)
#pragma unroll
            for (int e = 0; e < 8; ++e)
                qf[ks][e] = (short)qbase[(ks * 32 + quad * 8 + e) * 16];
    }

    floatx4 oacc[4];   // O[q=quad*4+r][hd=nt*16+l15]
#pragma unroll
    for (int nt = 0; nt < 4; ++nt) oacc[nt] = (floatx4){0.f, 0.f, 0.f, 0.f};
    floatx4 lacc = (floatx4){0.f, 0.f, 0.f, 0.f};   // l[q=quad*4+r]

    half8 vones;
#pragma unroll
    for (int i = 0; i < 8; ++i) vones[i] = (_Float16)1.0f;

    // staging: 8 waves x 64 lanes x 16B = one full 64-key subtile (K and V)
    const unsigned short* gk = Kb + (size_t)((w << 6) + lane) * 8;
    const unsigned short* gv = Vb + (size_t)((w << 6) + lane) * 8;
    unsigned short* lk[2] = { &Ks[0][w << 9], &Ks[1][w << 9] };
    unsigned short* lv[2] = { &Vs[0][w << 9], &Vs[1][w << 9] };

    // prologue: DMA subtile 0 into buffer 0
    __builtin_amdgcn_global_load_lds((GV*)(void*)gk, (LV*)(void*)lk[0], 16, 0, 0);
    __builtin_amdgcn_global_load_lds((GV*)(void*)gv, (LV*)(void*)lv[0], 16, 0, 0);

    for (int t = 0; t < 32; ++t) {
        const int buf = t & 1;
        __syncthreads();
        if (t < 31) {
            __builtin_amdgcn_global_load_lds((GV*)(void*)(gk + (t + 1) * 4096), (LV*)(void*)lk[buf ^ 1], 16, 0, 0);
            __builtin_amdgcn_global_load_lds((GV*)(void*)(gv + (t + 1) * 4096), (LV*)(void*)lv[buf ^ 1], 16, 0, 0);
        }
        const unsigned short* KsB = Ks[buf];
        const unsigned short* VsB = Vs[buf];

        // ---- S^T = K * Q^T over 64 keys
        floatx4 sacc[4];
#pragma unroll
        for (int nt = 0; nt < 4; ++nt) sacc[nt] = (floatx4){0.f, 0.f, 0.f, 0.f};

        __builtin_amdgcn_s_setprio(1);
#pragma unroll
        for (int ks = 0; ks < 2; ++ks) {
#pragma unroll
            for (int nt = 0; nt < 4; ++nt) {
                short8 kf = *(const short8*)(KsB + (nt * 2 + ks) * 512 + lane * 8);
                sacc[nt] = __builtin_amdgcn_mfma_f32_16x16x32_bf16(kf, qf[ks], sacc[nt], 0, 0, 0);
            }
        }
        __builtin_amdgcn_s_setprio(0);

        // ---- softmax + PV over 32-key groups (native 16x16x32 f16)
#pragma unroll
        for (int u = 0; u < 2; ++u) {
            floatx4 s0 = sacc[2 * u];
            floatx4 s1 = sacc[2 * u + 1];
            fp16x2 c0 = __builtin_amdgcn_cvt_pkrtz(ex2(s0[0]), ex2(s0[1]));
            fp16x2 c1 = __builtin_amdgcn_cvt_pkrtz(ex2(s0[2]), ex2(s0[3]));
            fp16x2 c2 = __builtin_amdgcn_cvt_pkrtz(ex2(s1[0]), ex2(s1[1]));
            fp16x2 c3 = __builtin_amdgcn_cvt_pkrtz(ex2(s1[2]), ex2(s1[3]));
            uint4v uu;
            uu.x = __builtin_bit_cast(unsigned int, c0);
            uu.y = __builtin_bit_cast(unsigned int, c1);
            uu.z = __builtin_bit_cast(unsigned int, c2);
            uu.w = __builtin_bit_cast(unsigned int, c3);
            half8 pf = __builtin_bit_cast(half8, uu);
            lacc = __builtin_amdgcn_mfma_f32_16x16x32_f16(pf, vones, lacc, 0, 0, 0);

            __builtin_amdgcn_s_setprio(1);
#pragma unroll
            for (int nt = 0; nt < 4; ++nt) {
                uint4v vv = *(const uint4v*)(VsB + (u * 4 + nt) * 512 + lane * 8);
                half8 vf = __builtin_bit_cast(half8, vv);
                oacc[nt] = __builtin_amdgcn_mfma_f32_16x16x32_f16(pf, vf, oacc[nt], 0, 0, 0);
            }
            __builtin_amdgcn_s_setprio(0);
        }
    }

    // ---- epilogue: O /= l, write bf16
    const int b = bh >> 4, h = bh & 15;
#pragma unroll
    for (int r = 0; r < 4; ++r) {
        float inv = 1.f / lacc[r];
        int n = q0 + w * 16 + quad * 4 + r;
        size_t rowoff = ((size_t)b * SEQ + n) * NDIM + h * HD;
#pragma unroll
        for (int nt = 0; nt < 4; ++nt)
            ob[rowoff + nt * 16 + l15] = f2bf(oacc[nt][r] * inv);
    }
}

// ---------------------------------------------------------------- launch
extern "C" void kernel_launch(void* const* d_in, const int* in_sizes, int n_in,
                              void* d_out, int out_size, void* d_ws, size_t ws_size,
                              hipStream_t stream)
{
    (void)in_sizes; (void)n_in; (void)out_size; (void)ws_size;
    const float* x    = (const float*)d_in[0];
    const float* wqkv = (const float*)d_in[1];
    const float* wout = (const float*)d_in[2];
    const float* bout = (const float*)d_in[3];
    float* out = (float*)d_out;

    unsigned short* xb    = (unsigned short*)d_ws;
    unsigned short* wqkvb = xb    + 8388608;
    unsigned short* woutb = wqkvb + 3145728;
    unsigned short* qbuf  = woutb + 1048576;
    unsigned short* kbuf  = qbuf  + 8388608;
    unsigned short* vbuf  = kbuf  + 8388608;
    unsigned short* obuf  = vbuf  + 8388608;

    cast_all<<<12288, 256, 0, stream>>>(x, wqkv, wout, xb);

    gemm_bt<0><<<dim3(64, 24), 256, 0, stream>>>(xb, wqkvb, qbuf, kbuf, vbuf, nullptr, nullptr);
    attn_fused<<<1024, 512, 0, stream>>>(qbuf, kbuf, vbuf, obuf);
    gemm_bt<1><<<dim3(64, 8), 256, 0, stream>>>(obuf, woutb, nullptr, nullptr, nullptr, bout, out);
}